// Round 8
// baseline (1612.834 us; speedup 1.0000x reference)
//
#include <hip/hip_runtime.h>
#include <math.h>

// ---------------- constants ----------------
#define T_STEPS 50
#define NB 512
#define RS2 0.70710678118654752f
#define INV_SQRT_L 0.40824829046386302f
#define WPACK_SHORT_OFF 36864    // d_ws offset in shorts (= float off 18432)

struct SchedArg { float cx0[T_STEPS], cxt[T_STEPS], sig[T_STEPS], s1m[T_STEPS], isab[T_STEPS]; };
struct FreqArg  { double f[64]; };

typedef short bf16x8 __attribute__((ext_vector_type(8)));
typedef float f32x4  __attribute__((ext_vector_type(4)));

__device__ __forceinline__ float4 ld4s(const float* p) { return *reinterpret_cast<const float4*>(p); }
__device__ __forceinline__ void   st4s(float* p, float4 v) { *reinterpret_cast<float4*>(p) = v; }
__device__ __forceinline__ float4 ld4g(const float* __restrict__ p) { return *reinterpret_cast<const float4*>(p); }
__device__ __forceinline__ float fast_sig(float x)  { return 1.f / (1.f + __expf(-x)); }
__device__ __forceinline__ float fast_tanh(float x) { float e = __expf(2.f * x); return 1.f - 2.f / (e + 1.f); }

__device__ __forceinline__ unsigned rne1(float f) {          // f32 -> bf16 bits (RNE)
    unsigned u = __float_as_uint(f);
    return (u + 0x7FFFu + ((u >> 16) & 1u)) >> 16;
}
__device__ __forceinline__ unsigned pk2(float a, float b) {
    return (rne1(a) & 0xFFFFu) | (rne1(b) << 16);
}
__device__ __forceinline__ void st_bf4(short* p, float a, float b, float c, float d) {
    uint2 v; v.x = pk2(a, b); v.y = pk2(c, d);
    *reinterpret_cast<uint2*>(p) = v;
}
__device__ __forceinline__ f32x4 mma(bf16x8 a, bf16x8 b, f32x4 c) {
    return __builtin_amdgcn_mfma_f32_16x16x32_bf16(a, b, c, 0, 0, 0);
}
__device__ __forceinline__ f32x4 bias4(const float* __restrict__ p) {
    float4 b = ld4g(p);
    f32x4 r; r[0] = b.x; r[1] = b.y; r[2] = b.z; r[3] = b.w;
    return r;
}
__device__ __forceinline__ bf16x8 ldfrag(const short* p) {
    return *reinterpret_cast<const bf16x8*>(p);
}

// ---------------- kernel A: Student-t marginal fit ----------------
__global__ __launch_bounds__(256) void fit_kernel(const float* __restrict__ xh,
                                                  float* __restrict__ loc,
                                                  float* __restrict__ scalef) {
    int gid = blockIdx.x * 256 + threadIdx.x;
    int b = gid >> 7, d = gid & 127;
    const float* p = xh + (size_t)b * 192 * 128 + d;
    float s = 0.f;
    for (int t = 0; t < 192; ++t) s += p[t * 128];
    float m = s * (1.0f / 192.0f);
    float v = 0.f;
    for (int t = 0; t < 192; ++t) {
        float c = p[t * 128] - m; c *= c;
        v = (t == 0) ? c : 0.94f * v + (1.0f - 0.94f) * c;
    }
    loc[gid] = m;
    scalef[gid] = fmaxf(sqrtf(v * 0.5f), 1e-5f);
}

// ---------------- kernel B: per-t embedding -> cond[6][32] ----------------
__global__ __launch_bounds__(256) void temb_kernel(
    const float* __restrict__ w1, const float* __restrict__ b1,
    const float* __restrict__ w2, const float* __restrict__ b2,
    const float* __restrict__ wt, const float* __restrict__ bt,
    float* __restrict__ cond_all, FreqArg fq) {
    int t = blockIdx.x;
    int tid = threadIdx.x;
    __shared__ float pe[128], te1[512], te2[512];
    if (tid < 64) {
        double e = (double)t * fq.f[tid];
        pe[tid]      = (float)sin(e);
        pe[tid + 64] = (float)cos(e);
    }
    __syncthreads();
    for (int j = tid; j < 512; j += 256) {
        float acc = b1[j];
        for (int k = 0; k < 128; ++k) acc += pe[k] * w1[k * 512 + j];
        te1[j] = acc / (1.f + expf(-acc));
    }
    __syncthreads();
    for (int j = tid; j < 512; j += 256) {
        float acc = b2[j];
        for (int k = 0; k < 512; ++k) acc += te1[k] * w2[k * 512 + j];
        te2[j] = acc / (1.f + expf(-acc));
    }
    __syncthreads();
    if (tid < 192) {
        int l = tid >> 5, c = tid & 31;
        float acc = bt[l * 32 + c];
        const float* w = wt + (size_t)l * 512 * 32 + c;
        for (int k = 0; k < 512; ++k) acc += te2[k] * w[k * 32];
        cond_all[t * 192 + tid] = acc;
    }
}

// ---------------- kernel P: pack weights as bf16 A-fragments ----------------
// A-frag layout (v_mfma_f32_16x16x32_bf16): lane l elem j holds A[m=l&15][k=(l>>4)*8+j].
__global__ __launch_bounds__(256) void prep_kernel(
    const float* __restrict__ w_in, const float* __restrict__ lyr_wdil,
    const float* __restrict__ lyr_wout, const float* __restrict__ w_o1,
    const float* __restrict__ w_o2, short* __restrict__ wpack) {
    int gid = blockIdx.x * 256 + threadIdx.x;
    if (gid >= 58368) return;
    int j = gid & 7, l = (gid >> 3) & 63, frag = gid >> 9;
    int m = l & 15, k = (l >> 4) * 8 + j;
    float v;
    if (frag < 8) {
        int m2 = frag >> 2, ks = frag & 3;
        v = w_in[(m2 * 16 + m) * 128 + ks * 32 + k];
    } else if (frag < 80) {
        int fi = frag - 8;
        int li = fi / 12, rem = fi % 12;
        int mg = rem / 6, rem2 = rem % 6;
        int tp = rem2 >> 1, gf = rem2 & 1;
        int o = gf * 32 + mg * 16 + m;
        v = lyr_wdil[((li * 64 + o) * 32 + k) * 3 + tp];
    } else if (frag < 104) {
        int fi = frag - 80;
        int li = fi >> 2, mo = fi & 3;
        v = lyr_wout[li * 2048 + (mo * 16 + m) * 32 + k];
    } else if (frag < 106) {
        int m2 = frag - 104;
        v = w_o1[(m2 * 16 + m) * 32 + k] * INV_SQRT_L;
    } else {
        int m8 = frag - 106;
        v = w_o2[(m8 * 16 + m) * 32 + k];
    }
    wpack[gid] = (short)rne1(v);
}

// ---------------- kernel C: 50-step diffusion — ONE WAVE PER ROW, zero barriers ----------------
// block = 64 (1 wave), grid = 512. All phase handoffs via wave-private LDS
// (same-wave DS ordering). x/h/skip state in registers as C-fragments.
__global__ __launch_bounds__(64, 1) void diffusion_kernel(
    const float* __restrict__ z_init, const float* __restrict__ noise,
    const float* __restrict__ b_in,  const float* __restrict__ lyr_bdil,
    const float* __restrict__ lyr_bout, const float* __restrict__ b_o1,
    const float* __restrict__ b_o2, const float* __restrict__ cond_all,
    const short* __restrict__ wpack, const float* __restrict__ loc,
    const float* __restrict__ scalef, float* __restrict__ out, SchedArg sc) {

    __shared__ __align__(16) float nzB[128 * 28];   // noise [d][28] f32; also init/epilogue bounce
    __shared__ __align__(16) short xbB[32 * 136];   // x bf16 [col][128d] (cols 24..31 pad)
    __shared__ __align__(16) short hcB[33 * 40];    // h+cond [col][32c]; col 32 = zeros
    __shared__ __align__(16) short actB[32 * 40];   // conv act / s bounce
    __shared__ __align__(16) short skB[32 * 40];    // skip bounce

    const int l  = threadIdx.x;         // 0..63
    const int ln = l & 15;
    const int lq = l >> 4;
    const int bb = blockIdx.x;          // row 0..511
    const int col0 = ln;                // n-tile 0 column (always valid h)
    const int col1 = 16 + ln;           // n-tile 1 column (valid iff ln<8)
    const int h1s  = (ln < 8) ? (16 + ln) : 0;   // safe h for n-tile 1 reads

    const short* wpP1 = wpack;
    const short* wpCv = wpack + 4096;
    const short* wpWo = wpack + 40960;
    const short* wpO1 = wpack + 53248;
    const short* wpO2 = wpack + 54272;

    // ---- hoisted step-invariant A-frags + biases ----
    bf16x8 aP1[2][4], aO1[2], aO2[8];
#pragma unroll
    for (int mt = 0; mt < 2; ++mt) {
#pragma unroll
        for (int ks = 0; ks < 4; ++ks)
            aP1[mt][ks] = ldfrag(wpP1 + (mt * 4 + ks) * 512 + l * 8);
        aO1[mt] = ldfrag(wpO1 + mt * 512 + l * 8);
    }
#pragma unroll
    for (int mt = 0; mt < 8; ++mt) aO2[mt] = ldfrag(wpO2 + mt * 512 + l * 8);
    f32x4 bIn[2], bO1v[2], bO2v[8];
#pragma unroll
    for (int mt = 0; mt < 2; ++mt) {
        bIn[mt]  = bias4(b_in + mt * 16 + lq * 4);
        bO1v[mt] = bias4(b_o1 + mt * 16 + lq * 4);
    }
#pragma unroll
    for (int mt = 0; mt < 8; ++mt) bO2v[mt] = bias4(b_o2 + mt * 16 + lq * 4);

    // ---- init: z_init (coalesced) -> nzB bounce -> x C-frags + xbB ----
    {
        const float* zg = z_init + (size_t)bb * 3072;
#pragma unroll
        for (int p = 0; p < 12; ++p) {
            int i0 = p * 256 + 4 * l;
            float4 v = ld4g(zg + i0);
            int d = i0 / 24, h = i0 - d * 24;   // float4 stays within one d-row (h%4==0)
            st4s(nzB + d * 28 + h, v);
        }
    }
    if (l < 40) hcB[32 * 40 + l] = 0;           // zero column for conv pad taps
    f32x4 xr[8][2];
#pragma unroll
    for (int mt = 0; mt < 8; ++mt) {
#pragma unroll
        for (int nt = 0; nt < 2; ++nt) {
            const int h = nt ? h1s : col0;
            const int d0 = mt * 16 + lq * 4;
            float v0 = nzB[(d0 + 0) * 28 + h];
            float v1 = nzB[(d0 + 1) * 28 + h];
            float v2 = nzB[(d0 + 2) * 28 + h];
            float v3 = nzB[(d0 + 3) * 28 + h];
            xr[mt][nt][0] = v0; xr[mt][nt][1] = v1; xr[mt][nt][2] = v2; xr[mt][nt][3] = v3;
            st_bf4(xbB + (nt ? col1 : col0) * 136 + d0, v0, v1, v2, v3);
        }
    }

    // ================= 50 diffusion steps, no barriers =================
    for (int step = 0; step < T_STEPS; ++step) {
        const int t = T_STEPS - 1 - step;
        const float* cndt = cond_all + t * 192;

        // issue this step's noise loads (coalesced); land during P1
        float4 nzl[12];
        {
            const float* nzg = noise + ((size_t)step * NB + bb) * 3072;
#pragma unroll
            for (int p = 0; p < 12; ++p) nzl[p] = ld4g(nzg + p * 256 + 4 * l);
        }

        // ---- P1: h = relu(Win @ x + b_in); write hc(li=0) ----
        f32x4 hr[2][2];
#pragma unroll
        for (int mt = 0; mt < 2; ++mt) {
#pragma unroll
            for (int nt = 0; nt < 2; ++nt) {
                const int col = nt ? col1 : col0;
                f32x4 acc = bIn[mt];
#pragma unroll
                for (int ks = 0; ks < 4; ++ks)
                    acc = mma(aP1[mt][ks], ldfrag(xbB + col * 136 + ks * 32 + lq * 8), acc);
#pragma unroll
                for (int i = 0; i < 4; ++i) acc[i] = fmaxf(acc[i], 0.f);
                hr[mt][nt] = acc;
                float4 cv = ld4g(cndt + mt * 16 + lq * 4);
                st_bf4(hcB + col * 40 + mt * 16 + lq * 4,
                       acc[0] + cv.x, acc[1] + cv.y, acc[2] + cv.z, acc[3] + cv.w);
            }
        }

        // ---- stage noise -> nzB (loads issued above have had P1 to land) ----
#pragma unroll
        for (int p = 0; p < 12; ++p) {
            int i0 = p * 256 + 4 * l;
            int d = i0 / 24, h = i0 - d * 24;
            st4s(nzB + d * 28 + h, nzl[p]);
        }

        f32x4 skr[2][2];
#pragma unroll
        for (int ms = 0; ms < 2; ++ms)
#pragma unroll
            for (int nt = 0; nt < 2; ++nt)
#pragma unroll
                for (int i = 0; i < 4; ++i) skr[ms][nt][i] = 0.f;

        // ---- 6 residual layers ----
#pragma unroll
        for (int li = 0; li < 6; ++li) {
            const int dd = 1 << li;
            // conv A-frags + biases (L2-hot)
            bf16x8 aCv[2][3][2];
#pragma unroll
            for (int mg = 0; mg < 2; ++mg)
#pragma unroll
                for (int tp = 0; tp < 3; ++tp)
#pragma unroll
                    for (int gf = 0; gf < 2; ++gf)
                        aCv[mg][tp][gf] = ldfrag(wpCv + (li * 12 + mg * 6 + tp * 2 + gf) * 512 + l * 8);
            f32x4 accg[2][2], accf[2][2];
#pragma unroll
            for (int mg = 0; mg < 2; ++mg) {
                f32x4 bg = bias4(lyr_bdil + li * 64 + mg * 16 + lq * 4);
                f32x4 bf = bias4(lyr_bdil + li * 64 + 32 + mg * 16 + lq * 4);
#pragma unroll
                for (int nt = 0; nt < 2; ++nt) { accg[mg][nt] = bg; accf[mg][nt] = bf; }
            }
            // 3 shifted K=32 GEMMs
#pragma unroll
            for (int nt = 0; nt < 2; ++nt) {
                const int hbase = nt * 16 + ln;
#pragma unroll
                for (int tp = 0; tp < 3; ++tp) {
                    if (li == 5 && tp != 1) continue;
                    int hh = hbase + (tp - 1) * dd;
                    int colp = ((unsigned)hh < 24u) ? hh : 32;
                    bf16x8 b = ldfrag(hcB + colp * 40 + lq * 8);
#pragma unroll
                    for (int mg = 0; mg < 2; ++mg) {
                        accg[mg][nt] = mma(aCv[mg][tp][0], b, accg[mg][nt]);
                        accf[mg][nt] = mma(aCv[mg][tp][1], b, accf[mg][nt]);
                    }
                }
            }
            // gated activation -> actB
#pragma unroll
            for (int mg = 0; mg < 2; ++mg)
#pragma unroll
                for (int nt = 0; nt < 2; ++nt) {
                    const int col = nt ? col1 : col0;
                    st_bf4(actB + col * 40 + mg * 16 + lq * 4,
                           fast_tanh(accf[mg][nt][0]) * fast_sig(accg[mg][nt][0]),
                           fast_tanh(accf[mg][nt][1]) * fast_sig(accg[mg][nt][1]),
                           fast_tanh(accf[mg][nt][2]) * fast_sig(accg[mg][nt][2]),
                           fast_tanh(accf[mg][nt][3]) * fast_sig(accg[mg][nt][3]));
                }
            // wout: res -> hr (regs), sk -> skr (regs), hc(li+1) -> hcB
            bf16x8 aWo[4];
            f32x4 bo[4];
#pragma unroll
            for (int mo = 0; mo < 4; ++mo) {
                aWo[mo] = ldfrag(wpWo + (li * 4 + mo) * 512 + l * 8);
                bo[mo]  = bias4(lyr_bout + li * 64 + mo * 16 + lq * 4);
            }
#pragma unroll
            for (int nt = 0; nt < 2; ++nt) {
                const int col = nt ? col1 : col0;
                bf16x8 b = ldfrag(actB + col * 40 + lq * 8);
#pragma unroll
                for (int mo = 0; mo < 4; ++mo) {
                    f32x4 acc = mma(aWo[mo], b, bo[mo]);
                    if (mo < 2) {
#pragma unroll
                        for (int i = 0; i < 4; ++i)
                            hr[mo][nt][i] = (hr[mo][nt][i] + acc[i]) * RS2;
                        if (li < 5) {
                            float4 cv = ld4g(cndt + (li + 1) * 32 + mo * 16 + lq * 4);
                            st_bf4(hcB + col * 40 + mo * 16 + lq * 4,
                                   hr[mo][nt][0] + cv.x, hr[mo][nt][1] + cv.y,
                                   hr[mo][nt][2] + cv.z, hr[mo][nt][3] + cv.w);
                        }
                    } else {
#pragma unroll
                        for (int i = 0; i < 4; ++i) skr[mo - 2][nt][i] += acc[i];
                    }
                }
            }
        }

        // ---- skip bounce -> skB; o1 -> actB ----
#pragma unroll
        for (int ms = 0; ms < 2; ++ms)
#pragma unroll
            for (int nt = 0; nt < 2; ++nt) {
                const int col = nt ? col1 : col0;
                st_bf4(skB + col * 40 + ms * 16 + lq * 4,
                       skr[ms][nt][0], skr[ms][nt][1], skr[ms][nt][2], skr[ms][nt][3]);
            }
#pragma unroll
        for (int nt = 0; nt < 2; ++nt) {
            const int col = nt ? col1 : col0;
            bf16x8 b = ldfrag(skB + col * 40 + lq * 8);
#pragma unroll
            for (int mt = 0; mt < 2; ++mt) {
                f32x4 acc = mma(aO1[mt], b, bO1v[mt]);
                st_bf4(actB + col * 40 + mt * 16 + lq * 4,
                       fmaxf(acc[0], 0.f), fmaxf(acc[1], 0.f),
                       fmaxf(acc[2], 0.f), fmaxf(acc[3], 0.f));
            }
        }

        // ---- o2: eps + fused DDPM x-update (regs) + xbB refresh ----
        {
            const float cx0 = sc.cx0[t], cxt = sc.cxt[t], sig = sc.sig[t];
            const float s1m = sc.s1m[t], isab = sc.isab[t];
#pragma unroll
            for (int nt = 0; nt < 2; ++nt) {
                const int col = nt ? col1 : col0;
                const int h = nt ? h1s : col0;
                bf16x8 b = ldfrag(actB + col * 40 + lq * 8);
#pragma unroll
                for (int mt = 0; mt < 8; ++mt) {
                    f32x4 acc = mma(aO2[mt], b, bO2v[mt]);
                    const int d0 = mt * 16 + lq * 4;
                    float xn[4];
#pragma unroll
                    for (int i = 0; i < 4; ++i) {
                        float nz = nzB[(d0 + i) * 28 + h];
                        float xv = xr[mt][nt][i];
                        float x0 = fminf(fmaxf((xv - s1m * acc[i]) * isab, -1.f), 1.f);
                        xn[i] = cx0 * x0 + cxt * xv + sig * nz;
                        xr[mt][nt][i] = xn[i];
                    }
                    st_bf4(xbB + col * 136 + d0, xn[0], xn[1], xn[2], xn[3]);
                }
            }
        }
    }

    // ---- epilogue: x C-frags -> nzB bounce -> t4ppf -> coalesced stores ----
#pragma unroll
    for (int mt = 0; mt < 8; ++mt)
#pragma unroll
        for (int nt = 0; nt < 2; ++nt) {
            if (nt == 1 && ln >= 8) continue;
            const int h = nt ? (16 + ln) : ln;
            const int d0 = mt * 16 + lq * 4;
#pragma unroll
            for (int i = 0; i < 4; ++i) nzB[(d0 + i) * 28 + h] = xr[mt][nt][i];
        }
    {
        const int b = bb & 31;
        const int d0e = 4 * (l & 31);
        const int hb = l >> 5;
        float4 l4 = ld4g(loc + b * 128 + d0e);
        float4 s4 = ld4g(scalef + b * 128 + d0e);
#pragma unroll
        for (int p = 0; p < 12; ++p) {
            const int h = 2 * p + hb;
            float4 o4;
#pragma unroll
            for (int e = 0; e < 4; ++e) {
                float z = nzB[(d0e + e) * 28 + h];
                float u = 0.5f * (1.f + erff(z * RS2));
                u = fminf(fmaxf(u, 1e-6f), 1.f - 1e-6f);
                float a4 = fminf(fmaxf(4.f * u * (1.f - u), 1e-12f), 1.f);
                float rr = sqrtf(a4);
                float q2 = 2.f * sqrtf(fmaxf(cosf(acosf(rr) * (1.f / 3.f)) / rr - 1.f, 0.f));
                float tstd = (u < 0.5f) ? -q2 : q2;
                (&o4.x)[e] = (&l4.x)[e] + (&s4.x)[e] * tstd;
            }
            *reinterpret_cast<float4*>(out + (size_t)bb * 3072 + h * 128 + d0e) = o4;
        }
    }
}

// ---------------- host ----------------
extern "C" void kernel_launch(void* const* d_in, const int* in_sizes, int n_in,
                              void* d_out, int out_size, void* d_ws, size_t ws_size,
                              hipStream_t stream) {
    const float* x_hist  = (const float*)d_in[0];
    const float* z_init  = (const float*)d_in[1];
    const float* noise   = (const float*)d_in[2];
    const float* w_in    = (const float*)d_in[3];
    const float* b_in    = (const float*)d_in[4];
    const float* temb_w1 = (const float*)d_in[5];
    const float* temb_b1 = (const float*)d_in[6];
    const float* temb_w2 = (const float*)d_in[7];
    const float* temb_b2 = (const float*)d_in[8];
    const float* lyr_wt  = (const float*)d_in[9];
    const float* lyr_bt  = (const float*)d_in[10];
    const float* lyr_wdil= (const float*)d_in[11];
    const float* lyr_bdil= (const float*)d_in[12];
    const float* lyr_wout= (const float*)d_in[13];
    const float* lyr_bout= (const float*)d_in[14];
    const float* w_o1    = (const float*)d_in[15];
    const float* b_o1    = (const float*)d_in[16];
    const float* w_o2    = (const float*)d_in[17];
    const float* b_o2    = (const float*)d_in[18];
    float* out = (float*)d_out;

    float* loc      = (float*)d_ws;                     // 4096 f32
    float* scalef   = loc + 4096;                       // 4096 f32
    float* cond_all = scalef + 4096;                    // 9600 f32
    short* wpack    = (short*)d_ws + WPACK_SHORT_OFF;   // 58368 bf16

    SchedArg sa;
    double abar = 1.0;
    for (int t = 0; t < T_STEPS; ++t) {
        double beta  = 1e-4 + (0.1 - 1e-4) * ((double)t / 49.0);
        double alpha = 1.0 - beta;
        double abprev = abar;
        abar *= alpha;
        sa.cx0[t]  = (float)(beta * sqrt(abprev) / (1.0 - abar));
        sa.cxt[t]  = (float)((1.0 - abprev) * sqrt(alpha) / (1.0 - abar));
        double pv  = beta * (1.0 - abprev) / (1.0 - abar);
        sa.sig[t]  = (t > 0) ? (float)sqrt(pv) : 0.f;
        sa.s1m[t]  = (float)sqrt(1.0 - abar);
        sa.isab[t] = (float)(1.0 / sqrt(abar));
    }
    FreqArg fa;
    for (int j = 0; j < 64; ++j) fa.f[j] = pow(10.0, (double)j * 4.0 / 63.0);

    prep_kernel<<<228, 256, 0, stream>>>(w_in, lyr_wdil, lyr_wout, w_o1, w_o2, wpack);
    fit_kernel<<<16, 256, 0, stream>>>(x_hist, loc, scalef);
    temb_kernel<<<T_STEPS, 256, 0, stream>>>(temb_w1, temb_b1, temb_w2, temb_b2,
                                             lyr_wt, lyr_bt, cond_all, fa);
    diffusion_kernel<<<NB, 64, 0, stream>>>(z_init, noise, b_in, lyr_bdil,
                                            lyr_bout, b_o1, b_o2, cond_all,
                                            wpack, loc, scalef, out, sa);
}

// Round 9
// 514.248 us; speedup vs baseline: 3.1363x; 3.1363x over previous
//
#include <hip/hip_runtime.h>
#include <math.h>

// ---------------- constants ----------------
#define T_STEPS 50
#define NB 512
#define RS2 0.70710678118654752f
#define INV_SQRT_L 0.40824829046386302f
#define WPACK_SHORT_OFF 36864    // d_ws offset in shorts (= float off 18432)

struct SchedArg { float cx0[T_STEPS], cxt[T_STEPS], sig[T_STEPS], s1m[T_STEPS], isab[T_STEPS]; };
struct FreqArg  { double f[64]; };

typedef short bf16x8 __attribute__((ext_vector_type(8)));
typedef float f32x4  __attribute__((ext_vector_type(4)));

__device__ __forceinline__ float4 ld4s(const float* p) { return *reinterpret_cast<const float4*>(p); }
__device__ __forceinline__ void   st4s(float* p, float4 v) { *reinterpret_cast<float4*>(p) = v; }
__device__ __forceinline__ float4 ld4g(const float* __restrict__ p) { return *reinterpret_cast<const float4*>(p); }
__device__ __forceinline__ float fast_sig(float x)  { return 1.f / (1.f + __expf(-x)); }
__device__ __forceinline__ float fast_tanh(float x) { float e = __expf(2.f * x); return 1.f - 2.f / (e + 1.f); }

__device__ __forceinline__ unsigned rne1(float f) {          // f32 -> bf16 bits (RNE)
    unsigned u = __float_as_uint(f);
    return (u + 0x7FFFu + ((u >> 16) & 1u)) >> 16;
}
__device__ __forceinline__ unsigned pk2(float a, float b) {
    return (rne1(a) & 0xFFFFu) | (rne1(b) << 16);
}
__device__ __forceinline__ void st_bf4(short* p, float a, float b, float c, float d) {
    uint2 v; v.x = pk2(a, b); v.y = pk2(c, d);
    *reinterpret_cast<uint2*>(p) = v;
}
__device__ __forceinline__ float bf2f(unsigned hi16) {
    return __uint_as_float(hi16 << 16);
}
__device__ __forceinline__ f32x4 mma(bf16x8 a, bf16x8 b, f32x4 c) {
    return __builtin_amdgcn_mfma_f32_16x16x32_bf16(a, b, c, 0, 0, 0);
}
__device__ __forceinline__ f32x4 bias4s(const float* p) {    // LDS float4 -> f32x4
    float4 b = ld4s(p);
    f32x4 r; r[0] = b.x; r[1] = b.y; r[2] = b.z; r[3] = b.w;
    return r;
}
__device__ __forceinline__ bf16x8 ldfrag(const short* p) {
    return *reinterpret_cast<const bf16x8*>(p);
}

// ---------------- kernel A: Student-t marginal fit ----------------
__global__ __launch_bounds__(256) void fit_kernel(const float* __restrict__ xh,
                                                  float* __restrict__ loc,
                                                  float* __restrict__ scalef) {
    int gid = blockIdx.x * 256 + threadIdx.x;
    int b = gid >> 7, d = gid & 127;
    const float* p = xh + (size_t)b * 192 * 128 + d;
    float s = 0.f;
    for (int t = 0; t < 192; ++t) s += p[t * 128];
    float m = s * (1.0f / 192.0f);
    float v = 0.f;
    for (int t = 0; t < 192; ++t) {
        float c = p[t * 128] - m; c *= c;
        v = (t == 0) ? c : 0.94f * v + (1.0f - 0.94f) * c;
    }
    loc[gid] = m;
    scalef[gid] = fmaxf(sqrtf(v * 0.5f), 1e-5f);
}

// ---------------- kernel B: per-t embedding -> cond[6][32] ----------------
__global__ __launch_bounds__(256) void temb_kernel(
    const float* __restrict__ w1, const float* __restrict__ b1,
    const float* __restrict__ w2, const float* __restrict__ b2,
    const float* __restrict__ wt, const float* __restrict__ bt,
    float* __restrict__ cond_all, FreqArg fq) {
    int t = blockIdx.x;
    int tid = threadIdx.x;
    __shared__ float pe[128], te1[512], te2[512];
    if (tid < 64) {
        double e = (double)t * fq.f[tid];
        pe[tid]      = (float)sin(e);
        pe[tid + 64] = (float)cos(e);
    }
    __syncthreads();
    for (int j = tid; j < 512; j += 256) {
        float acc = b1[j];
        for (int k = 0; k < 128; ++k) acc += pe[k] * w1[k * 512 + j];
        te1[j] = acc / (1.f + expf(-acc));
    }
    __syncthreads();
    for (int j = tid; j < 512; j += 256) {
        float acc = b2[j];
        for (int k = 0; k < 512; ++k) acc += te1[k] * w2[k * 512 + j];
        te2[j] = acc / (1.f + expf(-acc));
    }
    __syncthreads();
    if (tid < 192) {
        int l = tid >> 5, c = tid & 31;
        float acc = bt[l * 32 + c];
        const float* w = wt + (size_t)l * 512 * 32 + c;
        for (int k = 0; k < 512; ++k) acc += te2[k] * w[k * 32];
        cond_all[t * 192 + tid] = acc;
    }
}

// ---------------- kernel P: pack weights as bf16 A-fragments ----------------
// A-frag layout (v_mfma_f32_16x16x32_bf16): lane l elem j holds A[m=l&15][k=(l>>4)*8+j].
__global__ __launch_bounds__(256) void prep_kernel(
    const float* __restrict__ w_in, const float* __restrict__ lyr_wdil,
    const float* __restrict__ lyr_wout, const float* __restrict__ w_o1,
    const float* __restrict__ w_o2, short* __restrict__ wpack) {
    int gid = blockIdx.x * 256 + threadIdx.x;
    if (gid >= 58368) return;
    int j = gid & 7, l = (gid >> 3) & 63, frag = gid >> 9;
    int m = l & 15, k = (l >> 4) * 8 + j;
    float v;
    if (frag < 8) {
        int m2 = frag >> 2, ks = frag & 3;
        v = w_in[(m2 * 16 + m) * 128 + ks * 32 + k];
    } else if (frag < 80) {
        int fi = frag - 8;
        int li = fi / 12, rem = fi % 12;
        int mg = rem / 6, rem2 = rem % 6;
        int tp = rem2 >> 1, gf = rem2 & 1;
        int o = gf * 32 + mg * 16 + m;
        v = lyr_wdil[((li * 64 + o) * 32 + k) * 3 + tp];
    } else if (frag < 104) {
        int fi = frag - 80;
        int li = fi >> 2, mo = fi & 3;
        v = lyr_wout[li * 2048 + (mo * 16 + m) * 32 + k];
    } else if (frag < 106) {
        int m2 = frag - 104;
        v = w_o1[(m2 * 16 + m) * 32 + k] * INV_SQRT_L;
    } else {
        int m8 = frag - 106;
        v = w_o2[(m8 * 16 + m) * 32 + k];
    }
    wpack[gid] = (short)rne1(v);
}

// ---------------- kernel C: 50-step diffusion (MFMA), 2 rows/block, 8 waves ----------------
// R4 structure; all per-phase inputs (A-frags, biases, cond) pre-staged in
// registers/LDS so no phase begins with a global-memory-latency dependency.
__global__ __launch_bounds__(512, 2) void diffusion_kernel(
    const float* __restrict__ z_init, const float* __restrict__ noise,
    const float* __restrict__ b_in,  const float* __restrict__ lyr_bdil,
    const float* __restrict__ lyr_bout, const float* __restrict__ b_o1,
    const float* __restrict__ b_o2, const float* __restrict__ cond_all,
    const short* __restrict__ wpack, const float* __restrict__ loc,
    const float* __restrict__ scalef, float* __restrict__ out, SchedArg sc) {

    __shared__ __align__(16) float xsf[48 * 132];   // x f32 [col][128d]
    __shared__ __align__(16) short xbB[48 * 136];   // x bf16 [col][128k]
    __shared__ __align__(16) short hB [48 * 40];    // h bf16 [col][32c]
    __shared__ __align__(16) short hcB[49 * 40];    // h+cond; col 48 = zeros
    __shared__ __align__(16) short actB[48 * 40];   // conv act / s
    __shared__ __align__(16) short skB[48 * 40];    // skip accumulator
    __shared__ __align__(16) float biasB[960];      // b_in|bdil|bout|b_o1|b_o2
    __shared__ __align__(16) float condB[2][192];   // double-buffered cond[t]

    const int tid = threadIdx.x;
    const int wv  = __builtin_amdgcn_readfirstlane(tid >> 6);   // 0..7
    const int l   = tid & 63;
    const int ln  = l & 15;
    const int lq  = l >> 4;
    const int bb  = blockIdx.x;          // block -> rows bb*2, bb*2+1

    const short* wpP1 = wpack;
    const short* wpCv = wpack + 4096;
    const short* wpWo = wpack + 40960;
    const short* wpO1 = wpack + 53248;
    const short* wpO2 = wpack + 54272;

    const int m2   = wv / 3;             // P1/conv/o1 m-tile (waves 0..5)
    const int nn   = wv - 3 * m2;        // P1/conv/o1 n-tile
    const int colw = nn * 16 + ln;       // 0..47, always valid
    const int rw   = (colw >= 24) ? 1 : 0;
    const int hw   = colw - rw * 24;
    const int moW  = wv & 3;             // wout m-tile

    // ---- hoisted step-invariant A-frags ----
    bf16x8 aP1[4], aCv[6][3][2], aO1, aWo[6], aO2;
    if (wv < 6) {
#pragma unroll
        for (int ks = 0; ks < 4; ++ks)
            aP1[ks] = ldfrag(wpP1 + (m2 * 4 + ks) * 512 + l * 8);
        aO1 = ldfrag(wpO1 + m2 * 512 + l * 8);
#pragma unroll
        for (int li = 0; li < 6; ++li)
#pragma unroll
            for (int tp = 0; tp < 3; ++tp) {
                if (li == 5 && tp != 1) continue;
#pragma unroll
                for (int gf = 0; gf < 2; ++gf)
                    aCv[li][tp][gf] = ldfrag(wpCv + (li * 12 + m2 * 6 + tp * 2 + gf) * 512 + l * 8);
            }
    }
#pragma unroll
    for (int li = 0; li < 6; ++li)
        aWo[li] = ldfrag(wpWo + (li * 4 + moW) * 512 + l * 8);
    aO2 = ldfrag(wpO2 + wv * 512 + l * 8);

    // ---- init LDS: x, biases, cond[0], zero col ----
    for (int i = tid; i < 6144; i += 512) {
        int r = i / 3072, rem = i - r * 3072;
        int d = rem / 24, h = rem - d * 24;
        int col = r * 24 + h;
        float v = z_init[(size_t)bb * 6144 + i];
        xsf[col * 132 + d] = v;
        xbB[col * 136 + d] = (short)rne1(v);
    }
    for (int i = tid; i < 960; i += 512) {
        float v;
        if      (i < 32)  v = b_in[i];
        else if (i < 416) v = lyr_bdil[i - 32];
        else if (i < 800) v = lyr_bout[i - 416];
        else if (i < 832) v = b_o1[i - 800];
        else              v = b_o2[i - 832];
        biasB[i] = v;
    }
    if (tid < 192) condB[0][tid] = cond_all[(T_STEPS - 1) * 192 + tid];
    if (tid < 40) hcB[48 * 40 + tid] = 0;
    __syncthreads();

    for (int step = 0; step < T_STEPS; ++step) {
        const int t = T_STEPS - 1 - step;
        const float* cnd = condB[step & 1];

        // ======== P1: h = relu(Win @ x + b_in) -> hB,hcB | waves 6,7: housekeeping ========
        if (wv < 6) {
            f32x4 acc = bias4s(biasB + m2 * 16 + lq * 4);
            const short* xb = xbB + colw * 136;
#pragma unroll
            for (int ks = 0; ks < 4; ++ks)
                acc = mma(aP1[ks], ldfrag(xb + ks * 32 + lq * 8), acc);
            float h0 = fmaxf(acc[0], 0.f), h1 = fmaxf(acc[1], 0.f);
            float h2 = fmaxf(acc[2], 0.f), h3 = fmaxf(acc[3], 0.f);
            float4 cv = ld4s(cnd + m2 * 16 + lq * 4);
            st_bf4(hB + colw * 40 + m2 * 16 + lq * 4, h0, h1, h2, h3);
            st_bf4(hcB + colw * 40 + m2 * 16 + lq * 4,
                   h0 + cv.x, h1 + cv.y, h2 + cv.z, h3 + cv.w);
        } else {
            // zero skip accumulator (consumed last step by o1)
            for (int i = tid - 384; i < 960; i += 128)
                reinterpret_cast<unsigned*>(skB)[i] = 0u;
            // stage next step's cond
            if (step + 1 < T_STEPS) {
                for (int i = tid - 384; i < 192; i += 128)
                    condB[(step + 1) & 1][i] = cond_all[(t - 1) * 192 + i];
            }
        }
        __syncthreads();

        // ======== 6 residual layers ========
#pragma unroll
        for (int li = 0; li < 6; ++li) {
            const int dd = 1 << li;
            // ---- conv (shifted K=32 GEMMs) + gated act (waves 0..5) ----
            if (wv < 6) {
                f32x4 accg = bias4s(biasB + 32 + li * 64 + m2 * 16 + lq * 4);
                f32x4 accf = bias4s(biasB + 32 + li * 64 + 32 + m2 * 16 + lq * 4);
#pragma unroll
                for (int tp = 0; tp < 3; ++tp) {
                    if (li == 5 && tp != 1) continue;
                    int hh = hw + (tp - 1) * dd;
                    int colp = ((unsigned)hh < 24u) ? (rw * 24 + hh) : 48;
                    bf16x8 b = ldfrag(hcB + colp * 40 + lq * 8);
                    accg = mma(aCv[li][tp][0], b, accg);
                    accf = mma(aCv[li][tp][1], b, accf);
                }
                st_bf4(actB + colw * 40 + m2 * 16 + lq * 4,
                       fast_tanh(accf[0]) * fast_sig(accg[0]),
                       fast_tanh(accf[1]) * fast_sig(accg[1]),
                       fast_tanh(accf[2]) * fast_sig(accg[2]),
                       fast_tanh(accf[3]) * fast_sig(accg[3]));
            }
            __syncthreads();

            // ---- wout: 12 tiles (rep0: all 8 waves; rep1: waves 0..3, n=2) ----
#pragma unroll
            for (int rep = 0; rep < 2; ++rep) {
                int mo, col;
                bool active;
                if (rep == 0) { mo = moW; col = (wv >> 2) * 16 + ln; active = true; }
                else          { mo = wv;  col = 32 + ln;            active = (wv < 4); }
                if (active && !(li == 5 && mo < 2)) {
                    f32x4 bo = bias4s(biasB + 416 + li * 64 + mo * 16 + lq * 4);
                    f32x4 acc = mma(aWo[li], ldfrag(actB + col * 40 + lq * 8), bo);
                    if (mo < 2) {
                        short* hp = hB + col * 40 + mo * 16 + lq * 4;
                        uint2 hv = *reinterpret_cast<uint2*>(hp);
                        float n0 = (bf2f(hv.x & 0xFFFFu) + acc[0]) * RS2;
                        float n1 = (bf2f(hv.x >> 16)     + acc[1]) * RS2;
                        float n2 = (bf2f(hv.y & 0xFFFFu) + acc[2]) * RS2;
                        float n3 = (bf2f(hv.y >> 16)     + acc[3]) * RS2;
                        st_bf4(hp, n0, n1, n2, n3);
                        if (li < 5) {
                            float4 cv = ld4s(cnd + (li + 1) * 32 + mo * 16 + lq * 4);
                            st_bf4(hcB + col * 40 + mo * 16 + lq * 4,
                                   n0 + cv.x, n1 + cv.y, n2 + cv.z, n3 + cv.w);
                        }
                    } else {
                        short* sp = skB + col * 40 + (mo - 2) * 16 + lq * 4;
                        uint2 sv = *reinterpret_cast<uint2*>(sp);
                        st_bf4(sp,
                               bf2f(sv.x & 0xFFFFu) + acc[0],
                               bf2f(sv.x >> 16)     + acc[1],
                               bf2f(sv.y & 0xFFFFu) + acc[2],
                               bf2f(sv.y >> 16)     + acc[3]);
                    }
                }
            }
            __syncthreads();
        }

        // ======== o1: s = relu(b_o1 + Wo1s @ skip) -> actB (waves 0..5) ========
        if (wv < 6) {
            f32x4 acc = bias4s(biasB + 800 + m2 * 16 + lq * 4);
            acc = mma(aO1, ldfrag(skB + colw * 40 + lq * 8), acc);
            st_bf4(actB + colw * 40 + m2 * 16 + lq * 4,
                   fmaxf(acc[0], 0.f), fmaxf(acc[1], 0.f),
                   fmaxf(acc[2], 0.f), fmaxf(acc[3], 0.f));
        }
        __syncthreads();

        // ======== o2: eps + fused DDPM x-update (all 8 waves, 3 n-tiles each) ========
        {
            const float cx0 = sc.cx0[t], cxt = sc.cxt[t], sig = sc.sig[t];
            const float s1m = sc.s1m[t], isab = sc.isab[t];
            const int d0 = wv * 16 + lq * 4;
            f32x4 bia = bias4s(biasB + 832 + d0);
#pragma unroll
            for (int n = 0; n < 3; ++n) {
                const int col = n * 16 + ln;
                const int r = (col >= 24) ? 1 : 0;
                const int h = col - r * 24;
                f32x4 acc = mma(aO2, ldfrag(actB + col * 40 + lq * 8), bia);
                float* xp = xsf + col * 132 + d0;
                float4 xv = ld4s(xp);
                const float* nzp = noise + ((size_t)step * NB + bb * 2 + r) * 3072 + h;
                float4 rr;
#pragma unroll
                for (int i = 0; i < 4; ++i) {
                    float xvv = (&xv.x)[i];
                    float nz = nzp[(d0 + i) * 24];
                    float x0 = fminf(fmaxf((xvv - s1m * acc[i]) * isab, -1.f), 1.f);
                    (&rr.x)[i] = cx0 * x0 + cxt * xvv + sig * nz;
                }
                st4s(xp, rr);
                st_bf4(xbB + col * 136 + d0, rr.x, rr.y, rr.z, rr.w);
            }
        }
        __syncthreads();
    }

    // ---- epilogue: Gaussian -> Student-t4, coalesced writes ----
    {
        const int b = (bb * 2) & 31;
        for (int i = tid; i < 1536; i += 512) {
            int col = i >> 5, q = i & 31;
            int r = (col >= 24) ? 1 : 0;
            int h = col - r * 24;
            float4 zv = ld4s(xsf + col * 132 + q * 4);
            float4 l4 = ld4g(loc + (b + r) * 128 + q * 4);
            float4 s4 = ld4g(scalef + (b + r) * 128 + q * 4);
            float4 o4;
#pragma unroll
            for (int e = 0; e < 4; ++e) {
                float u = 0.5f * (1.f + erff((&zv.x)[e] * RS2));
                u = fminf(fmaxf(u, 1e-6f), 1.f - 1e-6f);
                float a4 = fminf(fmaxf(4.f * u * (1.f - u), 1e-12f), 1.f);
                float rr = sqrtf(a4);
                float q2 = 2.f * sqrtf(fmaxf(cosf(acosf(rr) * (1.f / 3.f)) / rr - 1.f, 0.f));
                float tstd = (u < 0.5f) ? -q2 : q2;
                (&o4.x)[e] = (&l4.x)[e] + (&s4.x)[e] * tstd;
            }
            *reinterpret_cast<float4*>(out + ((size_t)(bb * 2 + r) * 24 + h) * 128 + q * 4) = o4;
        }
    }
}

// ---------------- host ----------------
extern "C" void kernel_launch(void* const* d_in, const int* in_sizes, int n_in,
                              void* d_out, int out_size, void* d_ws, size_t ws_size,
                              hipStream_t stream) {
    const float* x_hist  = (const float*)d_in[0];
    const float* z_init  = (const float*)d_in[1];
    const float* noise   = (const float*)d_in[2];
    const float* w_in    = (const float*)d_in[3];
    const float* b_in    = (const float*)d_in[4];
    const float* temb_w1 = (const float*)d_in[5];
    const float* temb_b1 = (const float*)d_in[6];
    const float* temb_w2 = (const float*)d_in[7];
    const float* temb_b2 = (const float*)d_in[8];
    const float* lyr_wt  = (const float*)d_in[9];
    const float* lyr_bt  = (const float*)d_in[10];
    const float* lyr_wdil= (const float*)d_in[11];
    const float* lyr_bdil= (const float*)d_in[12];
    const float* lyr_wout= (const float*)d_in[13];
    const float* lyr_bout= (const float*)d_in[14];
    const float* w_o1    = (const float*)d_in[15];
    const float* b_o1    = (const float*)d_in[16];
    const float* w_o2    = (const float*)d_in[17];
    const float* b_o2    = (const float*)d_in[18];
    float* out = (float*)d_out;

    float* loc      = (float*)d_ws;                     // 4096 f32
    float* scalef   = loc + 4096;                       // 4096 f32
    float* cond_all = scalef + 4096;                    // 9600 f32
    short* wpack    = (short*)d_ws + WPACK_SHORT_OFF;   // 58368 bf16

    SchedArg sa;
    double abar = 1.0;
    for (int t = 0; t < T_STEPS; ++t) {
        double beta  = 1e-4 + (0.1 - 1e-4) * ((double)t / 49.0);
        double alpha = 1.0 - beta;
        double abprev = abar;
        abar *= alpha;
        sa.cx0[t]  = (float)(beta * sqrt(abprev) / (1.0 - abar));
        sa.cxt[t]  = (float)((1.0 - abprev) * sqrt(alpha) / (1.0 - abar));
        double pv  = beta * (1.0 - abprev) / (1.0 - abar);
        sa.sig[t]  = (t > 0) ? (float)sqrt(pv) : 0.f;
        sa.s1m[t]  = (float)sqrt(1.0 - abar);
        sa.isab[t] = (float)(1.0 / sqrt(abar));
    }
    FreqArg fa;
    for (int j = 0; j < 64; ++j) fa.f[j] = pow(10.0, (double)j * 4.0 / 63.0);

    prep_kernel<<<228, 256, 0, stream>>>(w_in, lyr_wdil, lyr_wout, w_o1, w_o2, wpack);
    fit_kernel<<<16, 256, 0, stream>>>(x_hist, loc, scalef);
    temb_kernel<<<T_STEPS, 256, 0, stream>>>(temb_w1, temb_b1, temb_w2, temb_b2,
                                             lyr_wt, lyr_bt, cond_all, fa);
    diffusion_kernel<<<256, 512, 0, stream>>>(z_init, noise, b_in, lyr_bdil,
                                              lyr_bout, b_o1, b_o2, cond_all,
                                              wpack, loc, scalef, out, sa);
}